// Round 1
// baseline (4276.305 us; speedup 1.0000x reference)
//
#include <hip/hip_runtime.h>
#include <hip/hip_bf16.h>

// Problem constants (from reference)
constexpr int B_   = 2;
constexpr int N_   = 50000;
constexpr int D_   = 64;     // D_IN == D_OUT == 64
constexpr int K_   = 3;
constexpr int E_   = 800000;
constexpr float INV_SQRT_2 = 0.70710678118654752440f;

// ---------------------------------------------------------------------------
// Kernel A: per-node transform.
//   out[b,n,o,k]    = INV_SQRT_2 * sum_i W_node[o,i] * x[b,n,i,k]
//   y_edge[b,n,o,k] =              sum_i W_edge[o,i] * x[b,n,i,k]
// One wave (64 lanes) per node; lane == o. W staged transposed in LDS
// (padded +1 to kill bank conflicts on both the transposing write and the
// per-iteration read). x staged per-wave in LDS, read as broadcast.
// ---------------------------------------------------------------------------
__global__ __launch_bounds__(256) void node_transform_kernel(
    const float* __restrict__ x,
    const float* __restrict__ Wn,
    const float* __restrict__ We,
    float* __restrict__ out,
    float* __restrict__ y_edge)
{
    __shared__ float WtN[64][65];   // Wt[i][o], padded
    __shared__ float WtE[64][65];
    __shared__ float xs[4][192];    // per-wave x staging

    // Stage W transposed: coalesced global read, conflict-free LDS write
    for (int t = threadIdx.x; t < 4096; t += 256) {
        int o = t >> 6, i = t & 63;
        WtN[i][o] = Wn[t];
        WtE[i][o] = We[t];
    }
    __syncthreads();

    const int wave = threadIdx.x >> 6;   // 0..3
    const int lane = threadIdx.x & 63;   // == o
    const int total = B_ * N_;           // 100000 node-batches

    for (int base = blockIdx.x * 4; base < total; base += gridDim.x * 4) {
        const int node = base + wave;    // flat (b*N + n)
        if (node < total) {
            // stage this wave's x (192 floats, 3 per lane, coalesced)
            const float* xp = x + (size_t)node * 192;
            xs[wave][lane]       = xp[lane];
            xs[wave][lane + 64]  = xp[lane + 64];
            xs[wave][lane + 128] = xp[lane + 128];
            // wave-local write->read; compiler inserts lgkmcnt waits

            float an0 = 0.f, an1 = 0.f, an2 = 0.f;
            float ae0 = 0.f, ae1 = 0.f, ae2 = 0.f;
            #pragma unroll
            for (int i = 0; i < 64; ++i) {
                float wn = WtN[i][lane];          // conflict-free
                float we = WtE[i][lane];
                float x0 = xs[wave][i * 3 + 0];   // broadcast
                float x1 = xs[wave][i * 3 + 1];
                float x2 = xs[wave][i * 3 + 2];
                an0 = fmaf(wn, x0, an0);
                an1 = fmaf(wn, x1, an1);
                an2 = fmaf(wn, x2, an2);
                ae0 = fmaf(we, x0, ae0);
                ae1 = fmaf(we, x1, ae1);
                ae2 = fmaf(we, x2, ae2);
            }
            const size_t off = (size_t)node * 192 + (size_t)lane * 3;
            out[off + 0] = an0 * INV_SQRT_2;
            out[off + 1] = an1 * INV_SQRT_2;
            out[off + 2] = an2 * INV_SQRT_2;
            y_edge[off + 0] = ae0;
            y_edge[off + 1] = ae1;
            y_edge[off + 2] = ae2;
        }
    }
}

// ---------------------------------------------------------------------------
// Kernel B: edge scatter.
//   out[b, dst[e], :, :] += INV_SQRT_2 * norm[dst[e]] * y_edge[b, src[e], :, :]
// 16 lanes per (edge, batch) pair; float4 gather (256B per 16-lane group),
// 4x atomicAdd f32 per float4. y_edge slab (76.8 MB) is L3-resident.
// ---------------------------------------------------------------------------
__global__ __launch_bounds__(256) void edge_scatter_kernel(
    const float* __restrict__ y_edge,
    const int* __restrict__ src,
    const int* __restrict__ dst,
    const float* __restrict__ norm,
    float* out)
{
    const int pair = blockIdx.x * 16 + (threadIdx.x >> 4);  // (e*2 + b)
    const int lane = threadIdx.x & 15;
    if (pair >= E_ * 2) return;

    const int e = pair >> 1;
    const int b = pair & 1;
    const int s = src[e];
    const int d = dst[e];
    const float scale = norm[d] * INV_SQRT_2;

    const float4* yp = (const float4*)(y_edge + ((size_t)b * N_ + s) * 192);
    float* op = out + ((size_t)b * N_ + d) * 192;

    #pragma unroll
    for (int j = 0; j < 3; ++j) {
        const int c = lane + 16 * j;        // 0..47 float4 chunks
        float4 v = yp[c];
        const int o4 = c * 4;
        atomicAdd(op + o4 + 0, v.x * scale);
        atomicAdd(op + o4 + 1, v.y * scale);
        atomicAdd(op + o4 + 2, v.z * scale);
        atomicAdd(op + o4 + 3, v.w * scale);
    }
}

extern "C" void kernel_launch(void* const* d_in, const int* in_sizes, int n_in,
                              void* d_out, int out_size, void* d_ws, size_t ws_size,
                              hipStream_t stream) {
    const float* x    = (const float*)d_in[0];
    const float* Wn   = (const float*)d_in[1];
    const float* We   = (const float*)d_in[2];
    const float* norm = (const float*)d_in[3];
    const int*   src  = (const int*)d_in[4];
    const int*   dst  = (const int*)d_in[5];
    float* out    = (float*)d_out;
    float* y_edge = (float*)d_ws;   // B*N*64*3 floats = 76.8 MB

    // Kernel A: 2048 blocks x 256 thr, grid-stride over 100000 node-batches
    node_transform_kernel<<<2048, 256, 0, stream>>>(x, Wn, We, out, y_edge);

    // Kernel B: 1.6M (edge,batch) pairs, 16 pairs per 256-thr block
    const int nblk = (E_ * 2) / 16;   // 100000 exactly
    edge_scatter_kernel<<<nblk, 256, 0, stream>>>(y_edge, src, dst, norm, out);
}

// Round 2
// 695.143 us; speedup vs baseline: 6.1517x; 6.1517x over previous
//
#include <hip/hip_runtime.h>
#include <hip/hip_bf16.h>

constexpr int B_ = 2;
constexpr int N_ = 50000;
constexpr int E_ = 800000;
constexpr float INV_SQRT_2 = 0.70710678118654752440f;

// ---------------------------------------------------------------------------
// Workspace layout (int32 elements):
//   counts     : [0, N)
//   offsets    : [N, 2N+1)
//   cursor     : [2N+1, 3N+1)
//   sorted_src : [3N+1, 3N+1+E)
// Total ~3.8 MB. Rebuilt every call (ws is re-poisoned before each launch).
// ---------------------------------------------------------------------------

__global__ __launch_bounds__(256) void zero_kernel(int* __restrict__ p, int n) {
    int i = blockIdx.x * 256 + threadIdx.x;
    if (i < n) p[i] = 0;
}

__global__ __launch_bounds__(256) void hist_kernel(const int* __restrict__ dst,
                                                   int* __restrict__ counts) {
    int e = blockIdx.x * 256 + threadIdx.x;
    if (e < E_) atomicAdd(&counts[dst[e]], 1);
}

// Single-block exclusive scan of counts[N] -> offsets[N+1].
__global__ __launch_bounds__(1024) void scan_kernel(const int* __restrict__ counts,
                                                    int* __restrict__ offsets) {
    __shared__ int part[1024];
    const int t = threadIdx.x;
    constexpr int CH = 49;                 // 1024*49 = 50176 >= N
    const int base = t * CH;
    int s = 0;
    for (int j = 0; j < CH; ++j) {
        int idx = base + j;
        if (idx < N_) s += counts[idx];
    }
    part[t] = s;
    __syncthreads();
    for (int off = 1; off < 1024; off <<= 1) {
        int v = (t >= off) ? part[t - off] : 0;
        __syncthreads();
        part[t] += v;
        __syncthreads();
    }
    int pre = part[t] - s;                 // exclusive prefix of this chunk
    for (int j = 0; j < CH; ++j) {
        int idx = base + j;
        if (idx < N_) { offsets[idx] = pre; pre += counts[idx]; }
    }
    if (t == 0) offsets[N_] = part[1023];  // == E
}

__global__ __launch_bounds__(256) void scatter_kernel(const int* __restrict__ src,
                                                      const int* __restrict__ dst,
                                                      const int* __restrict__ offsets,
                                                      int* __restrict__ cursor,
                                                      int* __restrict__ sorted_src) {
    int e = blockIdx.x * 256 + threadIdx.x;
    if (e < E_) {
        int d = dst[e];
        int pos = offsets[d] + atomicAdd(&cursor[d], 1);
        sorted_src[pos] = src[e];
    }
}

// ---------------------------------------------------------------------------
// Fused pull-aggregation + dual transform. One wave per (b, d) pair.
//   xagg[i,k] = sum_{e: dst=d} x[b, src[e], i, k]    (gather, register acc)
//   out[b,d,o,k] = INV_SQRT_2*( Wn[o,:].x[b,d,:,k] + norm[d]*We[o,:].xagg[:,k] )
// W staged transposed in LDS (pad 65 -> conflict-free column reads).
// Broadcast x / xagg read as float4 (3 reads per 4 i-steps instead of 12).
// ---------------------------------------------------------------------------
__global__ __launch_bounds__(256) void fused_kernel(
    const float* __restrict__ x,
    const float* __restrict__ Wn,
    const float* __restrict__ We,
    const float* __restrict__ norm,
    const int* __restrict__ offsets,
    const int* __restrict__ sorted_src,
    float* __restrict__ out)
{
    __shared__ float WtN[64][65];
    __shared__ float WtE[64][65];
    __shared__ float xs[4][192];
    __shared__ float xa[4][192];

    for (int t = threadIdx.x; t < 4096; t += 256) {
        int o = t >> 6, i = t & 63;
        WtN[i][o] = Wn[t];
        WtE[i][o] = We[t];
    }
    __syncthreads();

    const int wave = threadIdx.x >> 6;
    const int lane = threadIdx.x & 63;
    const int p = blockIdx.x * 4 + wave;       // 0..99999 exact
    const int b = p / N_;
    const int d = p - b * N_;

    // stage own node's x (broadcast source for the Wn term)
    const float* xp = x + (size_t)p * 192;
    xs[wave][lane]       = xp[lane];
    xs[wave][lane + 64]  = xp[lane + 64];
    xs[wave][lane + 128] = xp[lane + 128];

    // pull-aggregate neighbor x into registers (lane = i, 3 k's each)
    float a0 = 0.f, a1 = 0.f, a2 = 0.f;
    const int beg = offsets[d];
    const int end = offsets[d + 1];
    const float* xb = x + (size_t)b * N_ * 192 + lane * 3;
    for (int e = beg; e < end; ++e) {
        const float* q = xb + (size_t)sorted_src[e] * 192;
        a0 += q[0];
        a1 += q[1];
        a2 += q[2];
    }
    xa[wave][lane * 3 + 0] = a0;
    xa[wave][lane * 3 + 1] = a1;
    xa[wave][lane * 3 + 2] = a2;
    // wave-local LDS write->read ordering via lgkmcnt (same wave only)

    float an0 = 0.f, an1 = 0.f, an2 = 0.f;
    float ae0 = 0.f, ae1 = 0.f, ae2 = 0.f;
    const float4* xsv = (const float4*)&xs[wave][0];
    const float4* xav = (const float4*)&xa[wave][0];

    #pragma unroll
    for (int i4 = 0; i4 < 16; ++i4) {
        float4 d0 = xsv[i4 * 3 + 0];   // (i,k0..2),(i+1,k0)
        float4 d1 = xsv[i4 * 3 + 1];   // (i+1,k1..2),(i+2,k0..1)
        float4 d2 = xsv[i4 * 3 + 2];   // (i+2,k2),(i+3,k0..2)
        float4 g0 = xav[i4 * 3 + 0];
        float4 g1 = xav[i4 * 3 + 1];
        float4 g2 = xav[i4 * 3 + 2];
        float wn0 = WtN[4 * i4 + 0][lane];
        float wn1 = WtN[4 * i4 + 1][lane];
        float wn2 = WtN[4 * i4 + 2][lane];
        float wn3 = WtN[4 * i4 + 3][lane];
        float we0 = WtE[4 * i4 + 0][lane];
        float we1 = WtE[4 * i4 + 1][lane];
        float we2 = WtE[4 * i4 + 2][lane];
        float we3 = WtE[4 * i4 + 3][lane];

        an0 = fmaf(wn0, d0.x, an0); an1 = fmaf(wn0, d0.y, an1); an2 = fmaf(wn0, d0.z, an2);
        an0 = fmaf(wn1, d0.w, an0); an1 = fmaf(wn1, d1.x, an1); an2 = fmaf(wn1, d1.y, an2);
        an0 = fmaf(wn2, d1.z, an0); an1 = fmaf(wn2, d1.w, an1); an2 = fmaf(wn2, d2.x, an2);
        an0 = fmaf(wn3, d2.y, an0); an1 = fmaf(wn3, d2.z, an1); an2 = fmaf(wn3, d2.w, an2);

        ae0 = fmaf(we0, g0.x, ae0); ae1 = fmaf(we0, g0.y, ae1); ae2 = fmaf(we0, g0.z, ae2);
        ae0 = fmaf(we1, g0.w, ae0); ae1 = fmaf(we1, g1.x, ae1); ae2 = fmaf(we1, g1.y, ae2);
        ae0 = fmaf(we2, g1.z, ae0); ae1 = fmaf(we2, g1.w, ae1); ae2 = fmaf(we2, g2.x, ae2);
        ae0 = fmaf(we3, g2.y, ae0); ae1 = fmaf(we3, g2.z, ae1); ae2 = fmaf(we3, g2.w, ae2);
    }

    const float sc = norm[d];
    const size_t off = (size_t)p * 192 + (size_t)lane * 3;
    out[off + 0] = INV_SQRT_2 * fmaf(sc, ae0, an0);
    out[off + 1] = INV_SQRT_2 * fmaf(sc, ae1, an1);
    out[off + 2] = INV_SQRT_2 * fmaf(sc, ae2, an2);
}

extern "C" void kernel_launch(void* const* d_in, const int* in_sizes, int n_in,
                              void* d_out, int out_size, void* d_ws, size_t ws_size,
                              hipStream_t stream) {
    const float* x    = (const float*)d_in[0];
    const float* Wn   = (const float*)d_in[1];
    const float* We   = (const float*)d_in[2];
    const float* norm = (const float*)d_in[3];
    const int*   src  = (const int*)d_in[4];
    const int*   dst  = (const int*)d_in[5];
    float* out = (float*)d_out;

    int* ws_i       = (int*)d_ws;
    int* counts     = ws_i;
    int* offsets    = ws_i + N_;
    int* cursor     = ws_i + 2 * N_ + 1;
    int* sorted_src = ws_i + 3 * N_ + 1;

    // zero counts+offsets+cursor region: [0, 3N+1)
    const int nz = 3 * N_ + 1;
    zero_kernel<<<(nz + 255) / 256, 256, 0, stream>>>(ws_i, nz);

    const int eblk = (E_ + 255) / 256;   // 3125
    hist_kernel<<<eblk, 256, 0, stream>>>(dst, counts);
    scan_kernel<<<1, 1024, 0, stream>>>(counts, offsets);
    scatter_kernel<<<eblk, 256, 0, stream>>>(src, dst, offsets, cursor, sorted_src);

    // 100000 (b,d) pairs, 4 waves per 256-thread block
    fused_kernel<<<(B_ * N_) / 4, 256, 0, stream>>>(x, Wn, We, norm, offsets,
                                                    sorted_src, out);
}

// Round 3
// 434.142 us; speedup vs baseline: 9.8500x; 1.6012x over previous
//
#include <hip/hip_runtime.h>
#include <hip/hip_bf16.h>

constexpr int B_ = 2;
constexpr int N_ = 50000;
constexpr int E_ = 800000;
constexpr int NBLK_ = (N_ + 255) / 256;   // 196
constexpr float INV_SQRT_2 = 0.70710678118654752440f;

// ---------------------------------------------------------------------------
// Workspace layout (int32 elements):
//   counts     : [0, N)
//   cursor     : [N, 2N)          (adjacent to counts -> one zero pass)
//   offsets    : [2N, 3N+1)
//   bsum       : [3N+1, 3N+1+NBLK)
//   bsx        : [3N+1+NBLK, 3N+1+2*NBLK)
//   sorted_src : [3N+1+2*NBLK, +E)
// ---------------------------------------------------------------------------

__global__ __launch_bounds__(256) void zero_kernel(int* __restrict__ p, int n) {
    int i = blockIdx.x * 256 + threadIdx.x;
    if (i < n) p[i] = 0;
}

__global__ __launch_bounds__(256) void hist_kernel(const int* __restrict__ dst,
                                                   int* __restrict__ counts) {
    int e = blockIdx.x * 256 + threadIdx.x;
    if (e < E_) atomicAdd(&counts[dst[e]], 1);
}

// Parallel scan, phase 1: per-block (256-wide) reduction of counts.
__global__ __launch_bounds__(256) void scan_partial_kernel(const int* __restrict__ counts,
                                                           int* __restrict__ bsum) {
    __shared__ int w[4];
    int idx = blockIdx.x * 256 + threadIdx.x;
    int v = (idx < N_) ? counts[idx] : 0;
    #pragma unroll
    for (int o = 32; o; o >>= 1) v += __shfl_down(v, o, 64);
    if ((threadIdx.x & 63) == 0) w[threadIdx.x >> 6] = v;
    __syncthreads();
    if (threadIdx.x == 0) bsum[blockIdx.x] = w[0] + w[1] + w[2] + w[3];
}

// Phase 2: exclusive scan of the 196 block sums (single small block).
__global__ __launch_bounds__(256) void scan_bsum_kernel(const int* __restrict__ bsum,
                                                        int* __restrict__ bsx) {
    __shared__ int tmp[256];
    int t = threadIdx.x;
    int v = (t < NBLK_) ? bsum[t] : 0;
    tmp[t] = v;
    __syncthreads();
    #pragma unroll
    for (int off = 1; off < 256; off <<= 1) {
        int u = (t >= off) ? tmp[t - off] : 0;
        __syncthreads();
        tmp[t] += u;
        __syncthreads();
    }
    if (t < NBLK_) bsx[t] = tmp[t] - v;
}

// Phase 3: per-block exclusive scan + block prefix -> offsets.
__global__ __launch_bounds__(256) void scan_final_kernel(const int* __restrict__ counts,
                                                         const int* __restrict__ bsx,
                                                         int* __restrict__ offsets) {
    __shared__ int tmp[256];
    int idx = blockIdx.x * 256 + threadIdx.x;
    int t = threadIdx.x;
    int v = (idx < N_) ? counts[idx] : 0;
    tmp[t] = v;
    __syncthreads();
    #pragma unroll
    for (int off = 1; off < 256; off <<= 1) {
        int u = (t >= off) ? tmp[t - off] : 0;
        __syncthreads();
        tmp[t] += u;
        __syncthreads();
    }
    if (idx < N_) offsets[idx] = bsx[blockIdx.x] + tmp[t] - v;
    if (idx == N_ - 1) offsets[N_] = E_;   // total degree == E by construction
}

__global__ __launch_bounds__(256) void scatter_kernel(const int* __restrict__ src,
                                                      const int* __restrict__ dst,
                                                      const int* __restrict__ offsets,
                                                      int* __restrict__ cursor,
                                                      int* __restrict__ sorted_src) {
    int e = blockIdx.x * 256 + threadIdx.x;
    if (e < E_) {
        int d = dst[e];
        int pos = offsets[d] + atomicAdd(&cursor[d], 1);
        sorted_src[pos] = src[e];
    }
}

// ---------------------------------------------------------------------------
// Fused pull-aggregation + dual transform. One wave per (b, d) pair.
// 512-thread blocks (8 waves) share one LDS W-tile -> 45.6 KB/block ->
// 3 blocks/CU = 24 waves (75% occupancy). Gather: lanes 0..47 each own one
// float4 chunk of the 192-float node record; 4-edge unrolled -> 4 loads in
// flight per wave.
// ---------------------------------------------------------------------------
constexpr int WPB = 8;   // waves per block

__global__ __launch_bounds__(512, 6) void fused_kernel(
    const float* __restrict__ x,
    const float* __restrict__ Wn,
    const float* __restrict__ We,
    const float* __restrict__ norm,
    const int* __restrict__ offsets,
    const int* __restrict__ sorted_src,
    float* __restrict__ out)
{
    __shared__ float WtN[64][65];
    __shared__ float WtE[64][65];
    __shared__ float xs[WPB][192];
    __shared__ float xa[WPB][192];

    for (int t = threadIdx.x; t < 4096; t += 512) {
        int o = t >> 6, i = t & 63;
        WtN[i][o] = Wn[t];
        WtE[i][o] = We[t];
    }
    __syncthreads();

    const int wave = threadIdx.x >> 6;
    const int lane = threadIdx.x & 63;
    const int p = blockIdx.x * WPB + wave;   // 12500*8 = 100000 exact
    const int b = p / N_;
    const int d = p - b * N_;

    // stage own node's x (float4, lanes 0..47)
    const float* xp = x + (size_t)p * 192;
    if (lane < 48) {
        ((float4*)&xs[wave][0])[lane] = ((const float4*)xp)[lane];
    }

    // pull-aggregate neighbor x: lane owns float4 chunk `lane` (0..47)
    const int beg = offsets[d];
    const int end = offsets[d + 1];
    const float4* xb4 = (const float4*)(x + (size_t)b * N_ * 192);
    if (lane < 48) {
        float ax = 0.f, ay = 0.f, az = 0.f, aw = 0.f;
        int e = beg;
        for (; e + 3 < end; e += 4) {
            int s0 = sorted_src[e + 0];
            int s1 = sorted_src[e + 1];
            int s2 = sorted_src[e + 2];
            int s3 = sorted_src[e + 3];
            float4 v0 = xb4[(size_t)s0 * 48 + lane];
            float4 v1 = xb4[(size_t)s1 * 48 + lane];
            float4 v2 = xb4[(size_t)s2 * 48 + lane];
            float4 v3 = xb4[(size_t)s3 * 48 + lane];
            ax += v0.x + v1.x + v2.x + v3.x;
            ay += v0.y + v1.y + v2.y + v3.y;
            az += v0.z + v1.z + v2.z + v3.z;
            aw += v0.w + v1.w + v2.w + v3.w;
        }
        for (; e < end; ++e) {
            int s = sorted_src[e];
            float4 v = xb4[(size_t)s * 48 + lane];
            ax += v.x; ay += v.y; az += v.z; aw += v.w;
        }
        float4 a4; a4.x = ax; a4.y = ay; a4.z = az; a4.w = aw;
        ((float4*)&xa[wave][0])[lane] = a4;
    }
    // wave-local LDS write->read; compiler orders via lgkmcnt

    float an0 = 0.f, an1 = 0.f, an2 = 0.f;
    float ae0 = 0.f, ae1 = 0.f, ae2 = 0.f;
    const float4* xsv = (const float4*)&xs[wave][0];
    const float4* xav = (const float4*)&xa[wave][0];

    #pragma unroll
    for (int i4 = 0; i4 < 16; ++i4) {
        float4 d0 = xsv[i4 * 3 + 0];
        float4 d1 = xsv[i4 * 3 + 1];
        float4 d2 = xsv[i4 * 3 + 2];
        float4 g0 = xav[i4 * 3 + 0];
        float4 g1 = xav[i4 * 3 + 1];
        float4 g2 = xav[i4 * 3 + 2];
        float wn0 = WtN[4 * i4 + 0][lane];
        float wn1 = WtN[4 * i4 + 1][lane];
        float wn2 = WtN[4 * i4 + 2][lane];
        float wn3 = WtN[4 * i4 + 3][lane];
        float we0 = WtE[4 * i4 + 0][lane];
        float we1 = WtE[4 * i4 + 1][lane];
        float we2 = WtE[4 * i4 + 2][lane];
        float we3 = WtE[4 * i4 + 3][lane];

        an0 = fmaf(wn0, d0.x, an0); an1 = fmaf(wn0, d0.y, an1); an2 = fmaf(wn0, d0.z, an2);
        an0 = fmaf(wn1, d0.w, an0); an1 = fmaf(wn1, d1.x, an1); an2 = fmaf(wn1, d1.y, an2);
        an0 = fmaf(wn2, d1.z, an0); an1 = fmaf(wn2, d1.w, an1); an2 = fmaf(wn2, d2.x, an2);
        an0 = fmaf(wn3, d2.y, an0); an1 = fmaf(wn3, d2.z, an1); an2 = fmaf(wn3, d2.w, an2);

        ae0 = fmaf(we0, g0.x, ae0); ae1 = fmaf(we0, g0.y, ae1); ae2 = fmaf(we0, g0.z, ae2);
        ae0 = fmaf(we1, g0.w, ae0); ae1 = fmaf(we1, g1.x, ae1); ae2 = fmaf(we1, g1.y, ae2);
        ae0 = fmaf(we2, g1.z, ae0); ae1 = fmaf(we2, g1.w, ae1); ae2 = fmaf(we2, g2.x, ae2);
        ae0 = fmaf(we3, g2.y, ae0); ae1 = fmaf(we3, g2.z, ae1); ae2 = fmaf(we3, g2.w, ae2);
    }

    const float sc = norm[d];
    const size_t off = (size_t)p * 192 + (size_t)lane * 3;
    out[off + 0] = INV_SQRT_2 * fmaf(sc, ae0, an0);
    out[off + 1] = INV_SQRT_2 * fmaf(sc, ae1, an1);
    out[off + 2] = INV_SQRT_2 * fmaf(sc, ae2, an2);
}

extern "C" void kernel_launch(void* const* d_in, const int* in_sizes, int n_in,
                              void* d_out, int out_size, void* d_ws, size_t ws_size,
                              hipStream_t stream) {
    const float* x    = (const float*)d_in[0];
    const float* Wn   = (const float*)d_in[1];
    const float* We   = (const float*)d_in[2];
    const float* norm = (const float*)d_in[3];
    const int*   src  = (const int*)d_in[4];
    const int*   dst  = (const int*)d_in[5];
    float* out = (float*)d_out;

    int* ws_i       = (int*)d_ws;
    int* counts     = ws_i;
    int* cursor     = ws_i + N_;
    int* offsets    = ws_i + 2 * N_;
    int* bsum       = ws_i + 3 * N_ + 1;
    int* bsx        = bsum + NBLK_;
    int* sorted_src = bsx + NBLK_;

    // zero counts+cursor ([0, 2N))
    zero_kernel<<<(2 * N_ + 255) / 256, 256, 0, stream>>>(ws_i, 2 * N_);

    const int eblk = (E_ + 255) / 256;   // 3125
    hist_kernel<<<eblk, 256, 0, stream>>>(dst, counts);
    scan_partial_kernel<<<NBLK_, 256, 0, stream>>>(counts, bsum);
    scan_bsum_kernel<<<1, 256, 0, stream>>>(bsum, bsx);
    scan_final_kernel<<<NBLK_, 256, 0, stream>>>(counts, bsx, offsets);
    scatter_kernel<<<eblk, 256, 0, stream>>>(src, dst, offsets, cursor, sorted_src);

    // 100000 (b,d) pairs, 8 waves per 512-thread block
    fused_kernel<<<(B_ * N_) / WPB, 512, 0, stream>>>(x, Wn, We, norm, offsets,
                                                      sorted_src, out);
}